// Round 6
// baseline (122.469 us; speedup 1.0000x reference)
//
#include <hip/hip_runtime.h>
#include <hip/hip_bf16.h>
#include <stdint.h>

// ContrastiveLoss: N=8192, D=512 fp32 features, int labels {0,1}.
// out = mean_i [ (np_i * log(sum_exp_i) - sum_pos_i) / (np_i + 1e-8) ]
// R1..R16: fp8 tiles, upper-tri (2080 blocks), XCD swizzle, gload_lds
//     staging, [slot][row] PEP, coalesced final. champion 112.5 (sim 49.8).
// R17/R18: counted-vmcnt 3-buf pipeline -> sim 48.2 (flat; not drain-bound).
// R19: DPP row_ror epilogue reductions -> total 109.5 (sim ~45).
// R20/R21: MX MFMA + raw-barrier + (256,3) bound -> container died twice.
// R22: de-risked MX test: keep ONLY mfma_scale_f32_32x32x64_f8f6f4 (e4m3,
//     scales=1.0 E8M0 -> bit-identical math; correct for any hw k-layout
//     by A/B operand symmetry). Everything else champion-proven: 2-buffer
//     __syncthreads pipeline, no setprio, no forced occupancy bound.

#define N_ROWS 8192
#define DIMF 512
#define DIMB 512
#define NB 64
#define NSLOT 128
#define SIM_SCALE 0.0390625f   // 10 / 256  (features pre-scaled by 16)

typedef float f32x4 __attribute__((ext_vector_type(4)));
typedef float f32x16 __attribute__((ext_vector_type(16)));
typedef int i32x4 __attribute__((ext_vector_type(4)));
typedef int i32x8 __attribute__((ext_vector_type(8)));

__device__ static inline void gload_lds16(const uint8_t* g, uint8_t* l) {
    __builtin_amdgcn_global_load_lds(
        (const __attribute__((address_space(1))) unsigned int*)g,
        (__attribute__((address_space(3))) unsigned int*)l, 16, 0, 0);
}

// 16-lane rotate-reduce (VALU DPP row_ror, no LDS pipe). Proven R19.
__device__ static inline float rowsum16(float s) {
    s += __int_as_float(__builtin_amdgcn_update_dpp(
        0, __float_as_int(s), 0x128, 0xf, 0xf, false));
    s += __int_as_float(__builtin_amdgcn_update_dpp(
        0, __float_as_int(s), 0x124, 0xf, 0xf, false));
    s += __int_as_float(__builtin_amdgcn_update_dpp(
        0, __float_as_int(s), 0x122, 0xf, 0xf, false));
    s += __int_as_float(__builtin_amdgcn_update_dpp(
        0, __float_as_int(s), 0x121, 0xf, 0xf, false));
    return s;
}
// 32-lane sum (within lane&31 group): xor-16 shuffle + 16-lane DPP reduce.
__device__ static inline float rsum32(float s) {
    s += __shfl_xor(s, 16, 64);
    return rowsum16(s);
}

// 4 waves/block, one row per wave: fp32 sumsq -> scale by 16/norm -> fp8,
// k-permuted per 64B tile (row-uniform -> dot-invariant, A/B shared).
__global__ __launch_bounds__(256) void norm_kernel(const float* __restrict__ x,
                                                   uint8_t* __restrict__ f8,
                                                   float* __restrict__ out) {
    const int wave = threadIdx.x >> 6, t = threadIdx.x & 63;
    const int row = blockIdx.x * 4 + wave;
    const float4* xr = (const float4*)(x + (size_t)row * DIMF);
    float4 v0 = xr[2 * t];
    float4 v1 = xr[2 * t + 1];
    float ss = v0.x * v0.x + v0.y * v0.y + v0.z * v0.z + v0.w * v0.w +
               v1.x * v1.x + v1.y * v1.y + v1.z * v1.z + v1.w * v1.w;
#pragma unroll
    for (int off = 32; off >= 1; off >>= 1) ss += __shfl_xor(ss, off, 64);
    float s = 16.0f / fmaxf(sqrtf(ss), 1e-12f);
    int lo = 0, hi = 0;
    lo = __builtin_amdgcn_cvt_pk_fp8_f32(v0.x * s, v0.y * s, lo, false);
    lo = __builtin_amdgcn_cvt_pk_fp8_f32(v0.z * s, v0.w * s, lo, true);
    hi = __builtin_amdgcn_cvt_pk_fp8_f32(v1.x * s, v1.y * s, hi, false);
    hi = __builtin_amdgcn_cvt_pk_fp8_f32(v1.z * s, v1.w * s, hi, true);
    int2 pk;
    pk.x = lo;
    pk.y = hi;
    const int pos = (t >> 3) * 64 + (t & 3) * 16 + ((t >> 2) & 1) * 8;
    *(int2*)(f8 + (size_t)row * DIMB + pos) = pk;
    if (blockIdx.x == 0 && threadIdx.x == 0) out[0] = 0.0f;
}

// 128x128 tile/block, 4 waves 2x2, each 64x64 via 2x2 MFMA 32x32x64 MX-fp8
// (uniform 1.0 scales). BK=64B, champion 2-buffer __syncthreads pipeline:
// barrier at top of step kk drains the batch issued at step kk-1 (one
// compute phase of latency cover) -- the R9-proven structure.
__global__ __launch_bounds__(256) void sim_kernel(const uint8_t* __restrict__ f8,
                                                  const int* __restrict__ lab,
                                                  float2* __restrict__ PEP) {
    __shared__ __align__(16) uint8_t sA[2][128 * 64];
    __shared__ __align__(16) uint8_t sB[2][128 * 64];

    // XCD-locality swizzle (2080 = 8 * 260); decode upper-triangle index.
    const int tblk = (blockIdx.x & 7) * 260 + (blockIdx.x >> 3);
    int bi = (int)(64.5f - sqrtf(64.5f * 64.5f - 2.0f * (float)tblk));
    while (bi * (129 - bi) / 2 > tblk) --bi;
    while ((bi + 1) * (128 - bi) / 2 <= tblk) ++bi;
    const int bj = bi + (tblk - bi * (129 - bi) / 2);
    const bool diag = (bi == bj);

    const int t = threadIdx.x;
    const int iBase = bi * 128, jBase = bj * 128;
    const int lane = t & 63, wave = t >> 6;
    const int wm = wave >> 1, wn = wave & 1;
    const int r31 = lane & 31, h2 = lane >> 5;

    const int sub = lane >> 2;
    const int lu = (lane & 3) ^ ((sub >> 1) & 3);
    const size_t gA0 = (size_t)(iBase + wave * 32 + sub) * DIMB + lu * 16;
    const size_t gB0 = (size_t)(jBase + wave * 32 + sub) * DIMB + lu * 16;

    f32x16 acc2[2][2] = {};

    // Prologue: batch 0 into buffer 0.
#pragma unroll
    for (int c = 0; c < 2; ++c) {
        gload_lds16(f8 + gA0 + (size_t)(c * 16) * DIMB, sA[0] + (wave * 32 + c * 16) * 64);
        gload_lds16(f8 + gB0 + (size_t)(c * 16) * DIMB, sB[0] + (wave * 32 + c * 16) * 64);
    }

    // Read-side swizzle: global unit g lives at LDS unit g ^ ((row>>1)&3).
    const int x4 = (r31 >> 1) & 3;
    const int u0 = ((2 * h2) ^ x4) * 16;
    const int u1 = ((2 * h2 + 1) ^ x4) * 16;

#pragma unroll
    for (int kk = 0; kk < 8; ++kk) {
        const int cur = kk & 1;
        __syncthreads();
        if (kk < 7) {
#pragma unroll
            for (int c = 0; c < 2; ++c) {
                gload_lds16(f8 + gA0 + (size_t)(c * 16) * DIMB + (kk + 1) * 64,
                            sA[cur ^ 1] + (wave * 32 + c * 16) * 64);
                gload_lds16(f8 + gB0 + (size_t)(c * 16) * DIMB + (kk + 1) * 64,
                            sB[cur ^ 1] + (wave * 32 + c * 16) * 64);
            }
        }
        i32x8 av[2], bv[2];
#pragma unroll
        for (int mt = 0; mt < 2; ++mt) {
            const uint8_t* base = sA[cur] + (wm * 64 + mt * 32 + r31) * 64;
            i32x4 lo = *(const i32x4*)(base + u0);
            i32x4 hi = *(const i32x4*)(base + u1);
            av[mt] = __builtin_shufflevector(lo, hi, 0, 1, 2, 3, 4, 5, 6, 7);
        }
#pragma unroll
        for (int nt = 0; nt < 2; ++nt) {
            const uint8_t* base = sB[cur] + (wn * 64 + nt * 32 + r31) * 64;
            i32x4 lo = *(const i32x4*)(base + u0);
            i32x4 hi = *(const i32x4*)(base + u1);
            bv[nt] = __builtin_shufflevector(lo, hi, 0, 1, 2, 3, 4, 5, 6, 7);
        }
#pragma unroll
        for (int mt = 0; mt < 2; ++mt)
#pragma unroll
            for (int nt = 0; nt < 2; ++nt)
                acc2[mt][nt] = __builtin_amdgcn_mfma_scale_f32_32x32x64_f8f6f4(
                    av[mt], bv[nt], acc2[mt][nt], 0, 0,
                    0, 0x7F7F7F7F, 0, 0x7F7F7F7F);  // E8M0 1.0 scales
    }

    // Epilogue. 32x32 C/D layout: col = lane&31, row = (reg&3)+8*(reg>>2)
    // +4*(lane>>5). Per (mt): per-reg row partials over 2 nt cols, then
    // rsum32 across the 32-lane col group; writer lane c0 (bit2(c0)==h2)
    // selects its reg via cndmask chain -> coalesced 256B float2 store.
    const int c0 = r31;
    int labj[2];
#pragma unroll
    for (int nt = 0; nt < 2; ++nt) labj[nt] = lab[jBase + wn * 64 + nt * 32 + c0];

    const int slotR = 2 * bj + wn;  // rows of iBase
    const int slotC = 2 * bi + wm;  // cols of jBase
    float Ec[2] = {0, 0}, Pc[2] = {0, 0};
    const int rsel = (c0 & 3) | (((c0 >> 3) & 3) << 2);
    const bool rowWriter = (((c0 >> 2) & 1) == h2);

#pragma unroll
    for (int mt = 0; mt < 2; ++mt) {
        float Er[16], Pr[16];
        float wE = 0.0f, wP = 0.0f;
#pragma unroll
        for (int g = 0; g < 4; ++g) {
            const int4 li4 = *(const int4*)(lab + iBase + wm * 64 + mt * 32 + 8 * g + 4 * h2);
#pragma unroll
            for (int e = 0; e < 4; ++e) {
                const int r = 4 * g + e;
                const int labi = ((const int*)&li4)[e];
                float se = 0.0f, sp = 0.0f;
                if (diag) {
                    const int iloc = wm * 64 + mt * 32 + e + 8 * g + 4 * h2;
#pragma unroll
                    for (int nt = 0; nt < 2; ++nt) {
                        const int jloc = wn * 64 + nt * 32 + c0;
                        const float tv = acc2[mt][nt][r];
                        if (iloc != jloc) {
                            se += __expf(tv * SIM_SCALE);
                            if (labj[nt] == labi) sp += tv;
                        }
                    }
                } else {
#pragma unroll
                    for (int nt = 0; nt < 2; ++nt) {
                        const float tv = acc2[mt][nt][r];
                        const float ex = __expf(tv * SIM_SCALE);
                        se += ex;
                        Ec[nt] += ex;
                        if (labj[nt] == labi) {
                            sp += tv;
                            Pc[nt] += tv;
                        }
                    }
                }
                Er[r] = se;
                Pr[r] = sp;
            }
        }
#pragma unroll
        for (int r = 0; r < 16; ++r) {
            const float aE = rsum32(Er[r]);
            const float aP = rsum32(Pr[r]);
            if (rsel == r) { wE = aE; wP = aP; }
        }
        if (rowWriter) {
            float2 v;
            v.x = wE;
            v.y = wP * SIM_SCALE;
            PEP[(size_t)slotR * N_ROWS + iBase + wm * 64 + mt * 32 + c0] = v;
        }
    }

    if (!diag) {
#pragma unroll
        for (int nt = 0; nt < 2; ++nt) {
            Ec[nt] += __shfl_xor(Ec[nt], 32, 64);
            Pc[nt] += __shfl_xor(Pc[nt], 32, 64);
        }
        if (h2 == 0) {
#pragma unroll
            for (int nt = 0; nt < 2; ++nt) {
                float2 v;
                v.x = Ec[nt];
                v.y = Pc[nt] * SIM_SCALE;
                PEP[(size_t)slotC * N_ROWS + jBase + wn * 64 + nt * 32 + c0] = v;
            }
        }
    }
}

// 128 blocks x 64 rows, [slot][row] layout; coalesced 512B wave reads.
__global__ __launch_bounds__(256) void final_kernel(const float2* __restrict__ PEP,
                                                    const int* __restrict__ lab,
                                                    float* __restrict__ out) {
    __shared__ float sE[256], sP[256], sh[4];
    __shared__ float shc;
    const int t = threadIdx.x;
    const int rr = t & 63, q = t >> 6;

    int cl = 0;
#pragma unroll 8
    for (int s = t; s < N_ROWS; s += 256) cl += lab[s];
#pragma unroll
    for (int off = 32; off >= 1; off >>= 1) cl += __shfl_xor(cl, off, 64);
    if (rr == 0) sh[q] = (float)cl;
    __syncthreads();
    if (t == 0) shc = sh[0] + sh[1] + sh[2] + sh[3];

    const int r0 = blockIdx.x * 64;
    float se = 0.0f, sp = 0.0f;
#pragma unroll 8
    for (int v = 0; v < 32; ++v) {
        const float2 x = PEP[(size_t)(q * 32 + v) * N_ROWS + r0 + rr];
        se += x.x;
        sp += x.y;
    }
    sE[t] = se;
    sP[t] = sp;
    __syncthreads();

    float local = 0.0f;
    if (q == 0) {
        se = sE[rr] + sE[64 + rr] + sE[128 + rr] + sE[192 + rr];
        sp = sP[rr] + sP[64 + rr] + sP[128 + rr] + sP[192 + rr];
        const float c1 = shc;
        const int li = lab[r0 + rr];
        const float np = (li ? c1 : (float)N_ROWS - c1) - 1.0f;
        local = (np * __logf(se) - sp) / (np + 1e-8f);
#pragma unroll
        for (int off = 32; off >= 1; off >>= 1) local += __shfl_xor(local, off, 64);
    }
    if (t == 0) atomicAdd(out, local * (1.0f / (float)N_ROWS));
}

extern "C" void kernel_launch(void* const* d_in, const int* in_sizes, int n_in,
                              void* d_out, int out_size, void* d_ws, size_t ws_size,
                              hipStream_t stream) {
    const float* features = (const float*)d_in[0];
    const int* labels = (const int*)d_in[1];
    float* out = (float*)d_out;

    char* ws = (char*)d_ws;
    uint8_t* f8 = (uint8_t*)ws;                              // 4 MiB
    float2* PEP = (float2*)(ws + (size_t)N_ROWS * DIMB);     // 8 MiB [slot][row]

    norm_kernel<<<N_ROWS / 4, 256, 0, stream>>>(features, f8, out);
    sim_kernel<<<NB * (NB + 1) / 2, 256, 0, stream>>>(f8, labels, PEP);
    final_kernel<<<128, 256, 0, stream>>>(PEP, labels, out);
}

// Round 7
// 107.398 us; speedup vs baseline: 1.1403x; 1.1403x over previous
//
#include <hip/hip_runtime.h>
#include <hip/hip_bf16.h>
#include <stdint.h>

// ContrastiveLoss: N=8192, D=512 fp32 features, int labels {0,1}.
// out = mean_i [ (np_i * log(sum_exp_i) - sum_pos_i) / (np_i + 1e-8) ]
// R1..R19: fp8 tiles, upper-tri (2080 blocks), XCD swizzle, gload_lds
//     staging, [slot][row] PEP, DPP epilogue, coalesced final. 109.5 us
//     (sim ~45).
// R22: MX 32x32x64 validated numerically (absmax 0.0 -> operand-symmetry
//     argument holds) but regressed: SQ_LDS_BANK_CONFLICT 0 -> 2.13M
//     (exactly 4 cyc per b128 read), MfmaUtil 12%. Ad-hoc XOR swizzle for
//     the 2-units-per-row read pattern is structurally conflicted.
// R23: remove all layout guesswork. (1) norm writes TRANSPOSED global
//     f8t[g][row][16B] (g = dim/16); no k-permutation needed (A/B
//     symmetry makes any consistent k-mapping exact). (2) unit-major LDS
//     [unit][row][16B]: staging = contiguous 1024B wave-writes, fragment
//     reads = contiguous-row 16B/lane -- canonical zero-conflict both
//     ways, no swizzle. (3) mfma_scale 16x16x128 (same MX rate, K=128):
//     64 MFMA/wave and the 16x16 C/D layout back -> R19's DPP-only
//     epilogue verbatim (no shfl16 LDS traffic). BK=128, 64KB LDS.

#define N_ROWS 8192
#define DIMF 512
#define DIMB 512
#define NB 64
#define NSLOT 128
#define SIM_SCALE 0.0390625f   // 10 / 256  (features pre-scaled by 16)
#define UST (8192 * 16)        // f8t unit stride: one 16B unit for all rows

typedef float f32x4 __attribute__((ext_vector_type(4)));
typedef int i32x4 __attribute__((ext_vector_type(4)));
typedef int i32x8 __attribute__((ext_vector_type(8)));

__device__ static inline void gload_lds16(const uint8_t* g, uint8_t* l) {
    __builtin_amdgcn_global_load_lds(
        (const __attribute__((address_space(1))) unsigned int*)g,
        (__attribute__((address_space(3))) unsigned int*)l, 16, 0, 0);
}

// 16-lane rotate-reduce (VALU DPP row_ror, no LDS pipe). Proven R19.
__device__ static inline float rowsum16(float s) {
    s += __int_as_float(__builtin_amdgcn_update_dpp(
        0, __float_as_int(s), 0x128, 0xf, 0xf, false));
    s += __int_as_float(__builtin_amdgcn_update_dpp(
        0, __float_as_int(s), 0x124, 0xf, 0xf, false));
    s += __int_as_float(__builtin_amdgcn_update_dpp(
        0, __float_as_int(s), 0x122, 0xf, 0xf, false));
    s += __int_as_float(__builtin_amdgcn_update_dpp(
        0, __float_as_int(s), 0x121, 0xf, 0xf, false));
    return s;
}

// 4 waves/block, one row per wave: fp32 sumsq -> scale by 16/norm -> fp8.
// Output layout: f8t[g][row][16B], g = dim>>4 (unit-major transposed).
// Thread t holds dims 8t..8t+7 -> unit g = t>>1, half (t&1)*8.
__global__ __launch_bounds__(256) void norm_kernel(const float* __restrict__ x,
                                                   uint8_t* __restrict__ f8t,
                                                   float* __restrict__ out) {
    const int wave = threadIdx.x >> 6, t = threadIdx.x & 63;
    const int row = blockIdx.x * 4 + wave;
    const float4* xr = (const float4*)(x + (size_t)row * DIMF);
    float4 v0 = xr[2 * t];
    float4 v1 = xr[2 * t + 1];
    float ss = v0.x * v0.x + v0.y * v0.y + v0.z * v0.z + v0.w * v0.w +
               v1.x * v1.x + v1.y * v1.y + v1.z * v1.z + v1.w * v1.w;
#pragma unroll
    for (int off = 32; off >= 1; off >>= 1) ss += __shfl_xor(ss, off, 64);
    float s = 16.0f / fmaxf(sqrtf(ss), 1e-12f);
    int lo = 0, hi = 0;
    lo = __builtin_amdgcn_cvt_pk_fp8_f32(v0.x * s, v0.y * s, lo, false);
    lo = __builtin_amdgcn_cvt_pk_fp8_f32(v0.z * s, v0.w * s, lo, true);
    hi = __builtin_amdgcn_cvt_pk_fp8_f32(v1.x * s, v1.y * s, hi, false);
    hi = __builtin_amdgcn_cvt_pk_fp8_f32(v1.z * s, v1.w * s, hi, true);
    int2 pk;
    pk.x = lo;
    pk.y = hi;
    *(int2*)(f8t + (size_t)(t >> 1) * UST + (size_t)row * 16 + (t & 1) * 8) = pk;
    if (blockIdx.x == 0 && threadIdx.x == 0) out[0] = 0.0f;
}

// 128x128 tile/block, 4 waves 2x2, each 64x64 via 4x4 MFMA 16x16x128 MX-fp8
// (uniform 1.0 E8M0 scales -> exact). BK=128B (units 8kk..8kk+7), 2-buffer
// __syncthreads pipeline. LDS per side per buffer: [8 units][128 rows][16B]
// = 16KB; staging = contiguous 1024B wave-writes; fragment reads =
// contiguous rows -> canonical conflict-free.
__global__ __launch_bounds__(256) void sim_kernel(const uint8_t* __restrict__ f8t,
                                                  const int* __restrict__ lab,
                                                  float2* __restrict__ PEP) {
    __shared__ __align__(16) uint8_t sA[2][8 * 128 * 16];
    __shared__ __align__(16) uint8_t sB[2][8 * 128 * 16];

    // XCD-locality swizzle (2080 = 8 * 260); decode upper-triangle index.
    const int tblk = (blockIdx.x & 7) * 260 + (blockIdx.x >> 3);
    int bi = (int)(64.5f - sqrtf(64.5f * 64.5f - 2.0f * (float)tblk));
    while (bi * (129 - bi) / 2 > tblk) --bi;
    while ((bi + 1) * (128 - bi) / 2 <= tblk) ++bi;
    const int bj = bi + (tblk - bi * (129 - bi) / 2);
    const bool diag = (bi == bj);

    const int t = threadIdx.x;
    const int iBase = bi * 128, jBase = bj * 128;
    const int lane = t & 63, wave = t >> 6;
    const int wm = wave >> 1, wn = wave & 1;
    const int lrow = lane & 15, quad = lane >> 4;

    // Staging role: side = wave>>1 (0:A rows iBase, 1:B rows jBase),
    // half = wave&1 (rows h*64..h*64+63). 8 units per kk.
    const int sside = wave >> 1, shalf = wave & 1;
    const size_t gRow0 = (size_t)((sside ? jBase : iBase) + shalf * 64 + lane) * 16;
    uint8_t* ldsS = (sside ? sB[0] : sA[0]) + shalf * 1024;
    uint8_t* ldsS1 = (sside ? sB[1] : sA[1]) + shalf * 1024;

    f32x4 acc[4][4] = {};

    // Prologue: kk=0 (units 0..7) into buffer 0.
#pragma unroll
    for (int u = 0; u < 8; ++u)
        gload_lds16(f8t + (size_t)u * UST + gRow0, ldsS + u * 2048);

#pragma unroll
    for (int kk = 0; kk < 4; ++kk) {
        const int cur = kk & 1;
        __syncthreads();
        if (kk < 3) {
            uint8_t* dst = cur ? ldsS : ldsS1;
#pragma unroll
            for (int u = 0; u < 8; ++u)
                gload_lds16(f8t + (size_t)(8 * (kk + 1) + u) * UST + gRow0,
                            dst + u * 2048);
        }
        // Fragment reads: lane needs row (sub*16+lrow), k-quarter quad ->
        // units 2*quad, 2*quad+1. Contiguous 16B/lane across rows.
        i32x8 av[4], bv[4];
#pragma unroll
        for (int m = 0; m < 4; ++m) {
            const uint8_t* base =
                sA[cur] + (2 * quad) * 2048 + (wm * 64 + m * 16 + lrow) * 16;
            i32x4 lo = *(const i32x4*)base;
            i32x4 hi = *(const i32x4*)(base + 2048);
            av[m] = __builtin_shufflevector(lo, hi, 0, 1, 2, 3, 4, 5, 6, 7);
        }
#pragma unroll
        for (int n = 0; n < 4; ++n) {
            const uint8_t* base =
                sB[cur] + (2 * quad) * 2048 + (wn * 64 + n * 16 + lrow) * 16;
            i32x4 lo = *(const i32x4*)base;
            i32x4 hi = *(const i32x4*)(base + 2048);
            bv[n] = __builtin_shufflevector(lo, hi, 0, 1, 2, 3, 4, 5, 6, 7);
        }
#pragma unroll
        for (int m = 0; m < 4; ++m)
#pragma unroll
            for (int n = 0; n < 4; ++n)
                acc[m][n] = __builtin_amdgcn_mfma_scale_f32_16x16x128_f8f6f4(
                    av[m], bv[n], acc[m][n], 0, 0,
                    0, 0x7F7F7F7F, 0, 0x7F7F7F7F);  // E8M0 1.0 scales
    }

    // Register-only epilogue (R19 verbatim). C/D: col=lane&15, row=quad*4+e.
    // sp/spc accumulate RAW acc; SIM_SCALE applied once after reductions.
    int labj[4];
#pragma unroll
    for (int n = 0; n < 4; ++n) labj[n] = lab[jBase + wn * 64 + n * 16 + lrow];

    const int slotR = 2 * bj + wn;  // rows of iBase
    const int slotC = 2 * bi + wm;  // cols of jBase
    float sec[4] = {0, 0, 0, 0}, spc[4] = {0, 0, 0, 0};

#pragma unroll
    for (int m = 0; m < 4; ++m) {
        const int rbase = wm * 64 + m * 16 + quad * 4;
        const int4 li4 = *(const int4*)(lab + iBase + rbase);
        float rE[4], rP[4];
#pragma unroll
        for (int e = 0; e < 4; ++e) {
            const int labi = ((const int*)&li4)[e];
            float se = 0.0f, sp = 0.0f;
            if (diag) {
                const int i = iBase + rbase + e;
#pragma unroll
                for (int n = 0; n < 4; ++n) {
                    const int j = jBase + wn * 64 + n * 16 + lrow;
                    const float tv = acc[m][n][e];
                    if (j != i) {
                        se += __expf(tv * SIM_SCALE);
                        if (labj[n] == labi) sp += tv;
                    }
                }
            } else {
#pragma unroll
                for (int n = 0; n < 4; ++n) {
                    const float tv = acc[m][n][e];
                    const float ex = __expf(tv * SIM_SCALE);
                    se += ex;
                    sec[n] += ex;
                    if (labj[n] == labi) {
                        sp += tv;
                        spc[n] += tv;
                    }
                }
            }
            rE[e] = rowsum16(se);
            rP[e] = rowsum16(sp) * SIM_SCALE;
        }
        if (lrow == 0) {
            // 4 consecutive rows -> 32B contiguous (two float4 stores)
            float2* dst = &PEP[(size_t)slotR * N_ROWS + iBase + rbase];
            float4 v0 = {rE[0], rP[0], rE[1], rP[1]};
            float4 v1 = {rE[2], rP[2], rE[3], rP[3]};
            *(float4*)dst = v0;
            *(float4*)(dst + 2) = v1;
        }
    }

    if (!diag) {
#pragma unroll
        for (int n = 0; n < 4; ++n) {
            sec[n] += __shfl_xor(sec[n], 16, 64);
            sec[n] += __shfl_xor(sec[n], 32, 64);
            spc[n] += __shfl_xor(spc[n], 16, 64);
            spc[n] += __shfl_xor(spc[n], 32, 64);
        }
        if (quad == 0) {
            // 16 lanes x consecutive j -> 128B contiguous per n
#pragma unroll
            for (int n = 0; n < 4; ++n) {
                const int j = jBase + wn * 64 + n * 16 + lrow;
                float2 v;
                v.x = sec[n];
                v.y = spc[n] * SIM_SCALE;
                PEP[(size_t)slotC * N_ROWS + j] = v;
            }
        }
    }
}

// 128 blocks x 64 rows, [slot][row] layout; coalesced 512B wave reads.
__global__ __launch_bounds__(256) void final_kernel(const float2* __restrict__ PEP,
                                                    const int* __restrict__ lab,
                                                    float* __restrict__ out) {
    __shared__ float sE[256], sP[256], sh[4];
    __shared__ float shc;
    const int t = threadIdx.x;
    const int rr = t & 63, q = t >> 6;

    int cl = 0;
#pragma unroll 8
    for (int s = t; s < N_ROWS; s += 256) cl += lab[s];
#pragma unroll
    for (int off = 32; off >= 1; off >>= 1) cl += __shfl_xor(cl, off, 64);
    if (rr == 0) sh[q] = (float)cl;
    __syncthreads();
    if (t == 0) shc = sh[0] + sh[1] + sh[2] + sh[3];

    const int r0 = blockIdx.x * 64;
    float se = 0.0f, sp = 0.0f;
#pragma unroll 8
    for (int v = 0; v < 32; ++v) {
        const float2 x = PEP[(size_t)(q * 32 + v) * N_ROWS + r0 + rr];
        se += x.x;
        sp += x.y;
    }
    sE[t] = se;
    sP[t] = sp;
    __syncthreads();

    float local = 0.0f;
    if (q == 0) {
        se = sE[rr] + sE[64 + rr] + sE[128 + rr] + sE[192 + rr];
        sp = sP[rr] + sP[64 + rr] + sP[128 + rr] + sP[192 + rr];
        const float c1 = shc;
        const int li = lab[r0 + rr];
        const float np = (li ? c1 : (float)N_ROWS - c1) - 1.0f;
        local = (np * __logf(se) - sp) / (np + 1e-8f);
#pragma unroll
        for (int off = 32; off >= 1; off >>= 1) local += __shfl_xor(local, off, 64);
    }
    if (t == 0) atomicAdd(out, local * (1.0f / (float)N_ROWS));
}

extern "C" void kernel_launch(void* const* d_in, const int* in_sizes, int n_in,
                              void* d_out, int out_size, void* d_ws, size_t ws_size,
                              hipStream_t stream) {
    const float* features = (const float*)d_in[0];
    const int* labels = (const int*)d_in[1];
    float* out = (float*)d_out;

    char* ws = (char*)d_ws;
    uint8_t* f8t = (uint8_t*)ws;                             // 4 MiB transposed
    float2* PEP = (float2*)(ws + (size_t)N_ROWS * DIMB);     // 8 MiB [slot][row]

    norm_kernel<<<N_ROWS / 4, 256, 0, stream>>>(features, f8t, out);
    sim_kernel<<<NB * (NB + 1) / 2, 256, 0, stream>>>(f8t, labels, PEP);
    final_kernel<<<128, 256, 0, stream>>>(PEP, labels, out);
}